// Round 1
// baseline (919.592 us; speedup 1.0000x reference)
//
#include <hip/hip_runtime.h>

#define Bn 512
#define Tn 512
#define Dn 64
#define Hn 128
#define Ln 32
#define G4 512   // 4*Hn

typedef __attribute__((ext_vector_type(8))) short short8v;
typedef __attribute__((ext_vector_type(4))) float float4v;

__device__ __forceinline__ unsigned short f2bf(float f){
  unsigned int u = __float_as_uint(f);
  u += 0x7FFFu + ((u >> 16) & 1u);           // round-to-nearest-even
  return (unsigned short)(u >> 16);
}

__device__ __forceinline__ short8v pack8(float4v a, float4v b){
  short8v r;
  r[0]=(short)f2bf(a[0]); r[1]=(short)f2bf(a[1]);
  r[2]=(short)f2bf(a[2]); r[3]=(short)f2bf(a[3]);
  r[4]=(short)f2bf(b[0]); r[5]=(short)f2bf(b[1]);
  r[6]=(short)f2bf(b[2]); r[7]=(short)f2bf(b[3]);
  return r;
}

// B-fragment for mfma_f32_16x16x32_bf16: lane holds W[n = base+(lane&15)][k0 + 8*(lane>>4) + i]
__device__ __forceinline__ short8v load_wfrag(const float* __restrict__ W, int n, int k0, int ldk){
  const float* p = W + (size_t)n*(size_t)ldk + (size_t)k0;
  float4v a = *(const float4v*)p;
  float4v b = *(const float4v*)(p+4);
  return pack8(a,b);
}

__device__ __forceinline__ float4v mfma16(short8v a, short8v b, float4v c){
  return __builtin_amdgcn_mfma_f32_16x16x32_bf16(a, b, c, 0, 0, 0);
}

__device__ __forceinline__ float sigm(float v){
  return __builtin_amdgcn_rcpf(1.0f + __expf(-v));
}
__device__ __forceinline__ float tanh_(float v){
  // robust: v->+inf => 1, v->-inf => -1
  return 1.0f - 2.0f*__builtin_amdgcn_rcpf(1.0f + __expf(2.0f*v));
}

__global__ __launch_bounds__(256, 1) void vae_fused(
    const float* __restrict__ x,     const float* __restrict__ eps,
    const float* __restrict__ eW_ih, const float* __restrict__ eW_hh,
    const float* __restrict__ eb_ih, const float* __restrict__ eb_hh,
    const float* __restrict__ muW,   const float* __restrict__ mub,
    const float* __restrict__ lvW,   const float* __restrict__ lvb,
    const float* __restrict__ iW,    const float* __restrict__ ib,
    const float* __restrict__ dW_ih, const float* __restrict__ dW_hh,
    const float* __restrict__ db_ih, const float* __restrict__ db_hh,
    const float* __restrict__ oW,    const float* __restrict__ ob,
    float* __restrict__ out)
{
  // LDS: h tile [16][128] bf16 (XOR-swizzled), y tile [16][64] bf16 (swizzled),
  // gates [2][512] f32, small latent scratch.
  __shared__ __align__(16) unsigned short h_lds[16*128];
  __shared__ __align__(16) unsigned short y_lds[16*64];
  __shared__ __align__(16) float gates_s[2*G4];
  __shared__ __align__(16) float sc_h[2*Hn];
  __shared__ __align__(16) float sc_mu[2*Ln];
  __shared__ __align__(16) float sc_lv[2*Ln];
  __shared__ __align__(16) float sc_z[2*Ln];

  const int tid  = threadIdx.x;
  const int lane = tid & 63;
  const int w    = tid >> 6;          // wave 0..3, owns gate cols [w*128, w*128+128)
  const int m    = lane & 15;         // A/C fragment row
  const int q    = lane >> 4;         // k-group
  const int hswz = (m & 7) << 4;      // bank-conflict XOR swizzle
  const int b0   = blockIdx.x * 2;    // two batch rows per block

  // nonlinearity ownership: thread -> (row, j)
  const int nrow = tid >> 7;
  const int nj   = tid & 127;
  const int hwaddr = nrow*256 + ((nj*2) ^ ((nrow & 7) << 4));

  // ---- zero h/y LDS (rows 2..15 stay zero forever -> garbage C rows are benign) ----
  {
    int* hz = (int*)h_lds;
    #pragma unroll
    for (int idx = 0; idx < 4; ++idx) hz[tid + idx*256] = 0;
    int* yz = (int*)y_lds;
    #pragma unroll
    for (int idx = 0; idx < 2; ++idx) yz[tid + idx*256] = 0;
  }

  // ---- x prefetch (2 steps deep). All 16 fragment rows load (clamped); only rows 0,1 matter. ----
  const int xrow = (b0 + m < Bn) ? (b0 + m) : (Bn - 1);
  float4v xA0,xA1,xA2,xA3, xB0,xB1,xB2,xB3;
  {
    size_t xb = ((size_t)xrow*Tn + 0)*Dn + q*8;
    xA0 = *(const float4v*)(x + xb);      xA1 = *(const float4v*)(x + xb + 4);
    xA2 = *(const float4v*)(x + xb + 32); xA3 = *(const float4v*)(x + xb + 36);
    xb += Dn;
    xB0 = *(const float4v*)(x + xb);      xB1 = *(const float4v*)(x + xb + 4);
    xB2 = *(const float4v*)(x + xb + 32); xB3 = *(const float4v*)(x + xb + 36);
  }

  // ---- encoder weight fragments in VGPRs ----
  short8v wih[16];   // [nt 0..7][kt 0..1] : 4H x D
  short8v whh[32];   // [nt 0..7][kt 0..3] : 4H x H
  #pragma unroll
  for (int nt = 0; nt < 8; ++nt) {
    #pragma unroll
    for (int kt = 0; kt < 2; ++kt)
      wih[nt*2+kt] = load_wfrag(eW_ih, w*128 + nt*16 + m, kt*32 + q*8, Dn);
    #pragma unroll
    for (int kt = 0; kt < 4; ++kt)
      whh[nt*4+kt] = load_wfrag(eW_hh, w*128 + nt*16 + m, kt*32 + q*8, Hn);
  }

  float ebi = eb_ih[nj]      + eb_hh[nj];
  float ebf = eb_ih[Hn+nj]   + eb_hh[Hn+nj];
  float ebg = eb_ih[2*Hn+nj] + eb_hh[2*Hn+nj];
  float ebo = eb_ih[3*Hn+nj] + eb_hh[3*Hn+nj];

  float creg = 0.0f, hcur = 0.0f;
  __syncthreads();

#define READ_HFRAG(kb) (*(const short8v*)((const char*)h_lds + m*256 + (((kb) + q*16) ^ hswz)))
#define READ_YFRAG(kb) (*(const short8v*)((const char*)y_lds + m*128 + (((kb) + q*16) ^ hswz)))

#define GATES_MFMA(AF0, AF1) \
    short8v hf0 = READ_HFRAG(0);   short8v hf1 = READ_HFRAG(64); \
    short8v hf2 = READ_HFRAG(128); short8v hf3 = READ_HFRAG(192); \
    float4v acc[8]; \
    _Pragma("unroll") \
    for (int nt = 0; nt < 8; ++nt) { \
      float4v a = {0.f,0.f,0.f,0.f}; \
      a = mfma16((AF0), wih[nt*2+0], a); \
      a = mfma16((AF1), wih[nt*2+1], a); \
      a = mfma16(hf0, whh[nt*4+0], a); \
      a = mfma16(hf1, whh[nt*4+1], a); \
      a = mfma16(hf2, whh[nt*4+2], a); \
      a = mfma16(hf3, whh[nt*4+3], a); \
      acc[nt] = a; \
    } \
    if (lane < 16) { \
      _Pragma("unroll") \
      for (int nt = 0; nt < 8; ++nt) { \
        int col = w*128 + nt*16 + lane; \
        gates_s[col]      = acc[nt][0];  /* C row0 = reg0 (lanes 0-15) */ \
        gates_s[G4 + col] = acc[nt][1];  /* C row1 = reg1 */ \
      } \
    }

#define NONLIN() do { \
    float gi = gates_s[nrow*G4 + nj]        + ebi; \
    float gf = gates_s[nrow*G4 + Hn + nj]   + ebf; \
    float gg = gates_s[nrow*G4 + 2*Hn + nj] + ebg; \
    float go = gates_s[nrow*G4 + 3*Hn + nj] + ebo; \
    creg = sigm(gf)*creg + sigm(gi)*tanh_(gg); \
    hcur = sigm(go)*tanh_(creg); \
    *(unsigned short*)((char*)h_lds + hwaddr) = f2bf(hcur); \
  } while(0)

#define ENC_STEP(X0,X1,X2,X3, TPRE) do { \
    short8v xf0 = pack8(X0, X1); \
    short8v xf1 = pack8(X2, X3); \
    if ((TPRE) < Tn) { \
      size_t xb = ((size_t)xrow*Tn + (size_t)(TPRE))*Dn + q*8; \
      X0 = *(const float4v*)(x + xb);      X1 = *(const float4v*)(x + xb + 4); \
      X2 = *(const float4v*)(x + xb + 32); X3 = *(const float4v*)(x + xb + 36); \
    } \
    GATES_MFMA(xf0, xf1); \
    __syncthreads(); \
    NONLIN(); \
    __syncthreads(); \
  } while(0)

  // ================= encoder: 512 steps =================
  for (int t = 0; t < Tn; t += 2) {
    ENC_STEP(xA0,xA1,xA2,xA3, t+2);
    ENC_STEP(xB0,xB1,xB2,xB3, t+3);
  }

  // ================= latent: mu / log_var / z / decoder h0 =================
  sc_h[nrow*Hn + nj] = hcur;          // final encoder h in f32
  __syncthreads();

  if (tid < 128) {
    const int isLv = tid >> 6;
    const int r    = (tid >> 5) & 1;
    const int l    = tid & 31;
    const float* Wp = isLv ? lvW : muW;
    float s = isLv ? lvb[l] : mub[l];
    #pragma unroll
    for (int k = 0; k < Hn; k += 4) {
      float4v wv = *(const float4v*)(Wp + l*Hn + k);
      float4v hv = *(const float4v*)(sc_h + r*Hn + k);
      s += wv[0]*hv[0] + wv[1]*hv[1] + wv[2]*hv[2] + wv[3]*hv[3];
    }
    out[(size_t)Bn*Tn*Dn + (size_t)isLv*Bn*Ln + (size_t)(b0+r)*Ln + l] = s;
    (isLv ? sc_lv : sc_mu)[r*Ln + l] = s;
  }
  __syncthreads();

  if (tid < 64) {
    int r = tid >> 5, l = tid & 31;
    float zv = sc_mu[r*Ln+l] + eps[(size_t)(b0+r)*Ln + l] * __expf(0.5f * sc_lv[r*Ln+l]);
    sc_z[r*Ln+l] = zv;
  }
  __syncthreads();

  { // decoder hidden init (no activation); c = 0
    float s = ib[nj];
    #pragma unroll
    for (int l = 0; l < Ln; ++l) s += sc_z[nrow*Ln + l] * iW[nj*Ln + l];
    hcur = s; creg = 0.0f;
    *(unsigned short*)((char*)h_lds + hwaddr) = f2bf(hcur);
  }

  // ---- decoder weight fragments (overwrite encoder frags) ----
  #pragma unroll
  for (int nt = 0; nt < 8; ++nt) {
    #pragma unroll
    for (int kt = 0; kt < 2; ++kt)
      wih[nt*2+kt] = load_wfrag(dW_ih, w*128 + nt*16 + m, kt*32 + q*8, Dn);
    #pragma unroll
    for (int kt = 0; kt < 4; ++kt)
      whh[nt*4+kt] = load_wfrag(dW_hh, w*128 + nt*16 + m, kt*32 + q*8, Hn);
  }
  short8v ow0 = load_wfrag(oW, w*16 + m, 0*32 + q*8, Hn);
  short8v ow1 = load_wfrag(oW, w*16 + m, 1*32 + q*8, Hn);
  short8v ow2 = load_wfrag(oW, w*16 + m, 2*32 + q*8, Hn);
  short8v ow3 = load_wfrag(oW, w*16 + m, 3*32 + q*8, Hn);
  const float obv = ob[w*16 + m];

  ebi = db_ih[nj]      + db_hh[nj];
  ebf = db_ih[Hn+nj]   + db_hh[Hn+nj];
  ebg = db_ih[2*Hn+nj] + db_hh[2*Hn+nj];
  ebo = db_ih[3*Hn+nj] + db_hh[3*Hn+nj];

  __syncthreads();   // h_dec visible; y_lds still all-zero (first decoder input = 0)

  // ================= decoder: 512 autoregressive steps =================
  for (int i = 0; i < Tn; ++i) {
    // phase A: gates = y_prev @ dW_ih^T + h_prev @ dW_hh^T
    {
      short8v yf0 = READ_YFRAG(0);
      short8v yf1 = READ_YFRAG(64);
      GATES_MFMA(yf0, yf1);
    }
    __syncthreads();
    // phase B: nonlinearity -> h_i
    NONLIN();
    __syncthreads();
    // phase C: y_i = h_i @ out_W^T + out_b ; write to global + feed back via y_lds
    {
      short8v gf0 = READ_HFRAG(0);   short8v gf1 = READ_HFRAG(64);
      short8v gf2 = READ_HFRAG(128); short8v gf3 = READ_HFRAG(192);
      float4v oa = {0.f,0.f,0.f,0.f};
      oa = mfma16(gf0, ow0, oa);
      oa = mfma16(gf1, ow1, oa);
      oa = mfma16(gf2, ow2, oa);
      oa = mfma16(gf3, ow3, oa);
      if (lane < 16) {
        int col = w*16 + lane;
        float y0 = oa[0] + obv;
        float y1 = oa[1] + obv;
        out[((size_t)b0*Tn + (size_t)i)*Dn + col]     = y0;
        out[((size_t)(b0+1)*Tn + (size_t)i)*Dn + col] = y1;
        *(unsigned short*)((char*)y_lds + ((2*col) ^ 0))        = f2bf(y0);
        *(unsigned short*)((char*)y_lds + 128 + ((2*col) ^ 16)) = f2bf(y1);
      }
    }
    __syncthreads();
  }
#undef ENC_STEP
#undef NONLIN
#undef GATES_MFMA
#undef READ_HFRAG
#undef READ_YFRAG
}

extern "C" void kernel_launch(void* const* d_in, const int* in_sizes, int n_in,
                              void* d_out, int out_size, void* d_ws, size_t ws_size,
                              hipStream_t stream) {
  (void)in_sizes; (void)n_in; (void)d_ws; (void)ws_size; (void)out_size;
  const float* x     = (const float*)d_in[0];
  const float* eps   = (const float*)d_in[1];
  const float* eW_ih = (const float*)d_in[2];
  const float* eW_hh = (const float*)d_in[3];
  const float* eb_ih = (const float*)d_in[4];
  const float* eb_hh = (const float*)d_in[5];
  const float* muW   = (const float*)d_in[6];
  const float* mub   = (const float*)d_in[7];
  const float* lvW   = (const float*)d_in[8];
  const float* lvb   = (const float*)d_in[9];
  const float* iW    = (const float*)d_in[10];
  const float* ib    = (const float*)d_in[11];
  const float* dW_ih = (const float*)d_in[12];
  const float* dW_hh = (const float*)d_in[13];
  const float* db_ih = (const float*)d_in[14];
  const float* db_hh = (const float*)d_in[15];
  const float* oW    = (const float*)d_in[16];
  const float* ob    = (const float*)d_in[17];
  float* out = (float*)d_out;

  vae_fused<<<dim3(256), dim3(256), 0, stream>>>(
      x, eps, eW_ih, eW_hh, eb_ih, eb_hh, muW, mub, lvW, lvb,
      iW, ib, dW_ih, dW_hh, db_ih, db_hh, oW, ob, out);
}